// Round 8
// baseline (293.317 us; speedup 1.0000x reference)
//
#include <hip/hip_runtime.h>
#include <stdint.h>

#define N_NODES 16384
#define N_EDGES 4096
#define FDIM    128
#define EPSF    1e-6f

typedef __attribute__((ext_vector_type(8))) short short8;
typedef __attribute__((ext_vector_type(4))) float f32x4;
typedef unsigned long long ull;

__device__ __forceinline__ unsigned short f2bf(float f) {
    uint32_t u = __float_as_uint(f);
    return (unsigned short)((u + 0x7FFFu + ((u >> 16) & 1u)) >> 16);  // RNE
}
__device__ __forceinline__ short8 as_s8(uint4 v) {
    union { uint4 a; short8 b; } u; u.a = v; return u.b;
}

// Expand 8 H-bits (byte at bitoff of `half`) into 8 packed bf16 {0.0,1.0}.
__device__ __forceinline__ short8 expand8(uint32_t half, int bitoff) {
    uint32_t b8 = (half >> bitoff) & 0xFFu;
    uint32_t lo = ((b8 & 0xFu) * 0x00204081u) & 0x01010101u;
    uint32_t hi = ((b8 >> 4) * 0x00204081u) & 0x01010101u;
    union { short8 v; uint32_t u[4]; } a;
#if __has_builtin(__builtin_amdgcn_perm)
    a.u[0] = __builtin_amdgcn_perm(0u, lo, 0x04010400u) * 0x3F80u;
    a.u[1] = __builtin_amdgcn_perm(0u, lo, 0x04030402u) * 0x3F80u;
    a.u[2] = __builtin_amdgcn_perm(0u, hi, 0x04010400u) * 0x3F80u;
    a.u[3] = __builtin_amdgcn_perm(0u, hi, 0x04030402u) * 0x3F80u;
#else
    a.u[0] = ((lo & 1u)         | ((lo >> 8) & 1u) << 16) * 0x3F80u;
    a.u[1] = (((lo >> 16) & 1u) | ((lo >> 24) & 1u) << 16) * 0x3F80u;
    a.u[2] = ((hi & 1u)         | ((hi >> 8) & 1u) << 16) * 0x3F80u;
    a.u[3] = (((hi >> 16) & 1u) | ((hi >> 24) & 1u) << 16) * 0x3F80u;
#endif
    return a.v;
}

// 64x64 bit-matrix transpose across a wave: lane r holds row r; out(r,c)=in(c,r).
__device__ __forceinline__ ull bit_transpose64(ull q, int lane) {
    const ull M32 = 0xFFFFFFFF00000000ull, M16 = 0xFFFF0000FFFF0000ull,
              M8 = 0xFF00FF00FF00FF00ull, M4 = 0xF0F0F0F0F0F0F0F0ull,
              M2 = 0xCCCCCCCCCCCCCCCCull, M1 = 0xAAAAAAAAAAAAAAAAull;
#define TSTEP(d, Md) { ull tv = __shfl_xor(q, d, 64); \
    q = ((lane & d) == 0) ? ((q & ~Md) | ((tv << d) & Md)) \
                          : ((q & Md) | ((tv >> d) & ~Md)); }
    TSTEP(32, M32) TSTEP(16, M16) TSTEP(8, M8) TSTEP(4, M4) TSTEP(2, M2) TSTEP(1, M1)
#undef TSTEP
    return q;
}

// K1 (R2-verbatim): bitpack H rows -> bitsNE [N][E/64], permuted bit order
// p(j) = 4*(j&15) + (j>>4); exact d_v_inv via popcount. float4 loads (1KB/wave).
__global__ __launch_bounds__(256) void k_bitpack(const float* __restrict__ H,
        ull* __restrict__ bitsNE, float* __restrict__ dvinv) {
    int w = threadIdx.x >> 6, lane = threadIdx.x & 63;
    int n = blockIdx.x * 4 + w;
    const float4* hr = (const float4*)(H + (size_t)n * N_EDGES);
    ull* out = bitsNE + (size_t)n * (N_EDGES / 64);
    int cnt = 0;
    for (int c4 = 0; c4 < N_EDGES / 256; ++c4) {
        float4 v = hr[c4 * 64 + lane];
        ull b0 = __ballot(v.x > 0.5f);
        ull b1 = __ballot(v.y > 0.5f);
        ull b2 = __ballot(v.z > 0.5f);
        ull b3 = __ballot(v.w > 0.5f);
        cnt += __popcll(b0) + __popcll(b1) + __popcll(b2) + __popcll(b3);
        if (lane == 0) {
            #pragma unroll
            for (int q = 0; q < 4; ++q) {
                ull wq = ((b0 >> (16 * q)) & 0xFFFFull)
                       | (((b1 >> (16 * q)) & 0xFFFFull) << 16)
                       | (((b2 >> (16 * q)) & 0xFFFFull) << 32)
                       | (((b3 >> (16 * q)) & 0xFFFFull) << 48);
                out[c4 * 4 + q] = wq;
            }
        }
    }
    if (lane == 0) dvinv[n] = 1.0f / ((float)cnt + EPSF);
}

// K2 (R7-proven): butterfly bit transpose with permuted row indexing.
__global__ __launch_bounds__(256) void k_transpose_bf(const ull* __restrict__ bitsNE,
        ull* __restrict__ bitsEN) {
    int w = threadIdx.x >> 6, lane = threadIdx.x & 63;
    int wid = blockIdx.x * 4 + w;          // 0..2047
    int nt = wid >> 3, etg = wid & 7;
    int pl = 4 * (lane & 15) + (lane >> 4);
    const ull* src = bitsNE + (size_t)(nt * 64 + pl) * (N_EDGES / 64);
    #pragma unroll
    for (int i = 0; i < 8; ++i) {
        int et = etg * 8 + i;
        ull q = src[et];
        q = bit_transpose64(q, lane);
        bitsEN[(size_t)(et * 64 + pl) * (N_NODES / 64) + nt] = q;
    }
}

// K3 (R2-verbatim): edge degrees via popcount -> d_e_inv (exact).
__global__ __launch_bounds__(256) void k_edeg(const ull* __restrict__ bitsEN,
        float* __restrict__ deinv) {
    int w = threadIdx.x >> 6, lane = threadIdx.x & 63;
    int e = blockIdx.x * 4 + w;
    const ull* r = bitsEN + (size_t)e * (N_NODES / 64);
    int s = __popcll(r[lane]) + __popcll(r[lane + 64]) + __popcll(r[lane + 128]) + __popcll(r[lane + 192]);
    for (int o = 32; o; o >>= 1) s += __shfl_xor(s, o);
    if (lane == 0) deinv[e] = 1.0f / ((float)s + EPSF);
}

// K4 (R2-verbatim): xw = x @ W; transposed-permuted bf16 xwTp [128][N].
__global__ __launch_bounds__(256) void k_xw(const float* __restrict__ x, const float* __restrict__ W,
        unsigned short* __restrict__ xwTp) {
    __shared__ __attribute__((aligned(16))) unsigned short ldsWT[128 * 136];
    __shared__ __attribute__((aligned(16))) unsigned short ldsT[128 * 72];
    int t = threadIdx.x, lane = t & 63, w = t >> 6;
    int r16 = lane & 15, klane = lane >> 4;
    for (int i = 0; i < 64; ++i) {
        int idx = i * 256 + t;
        int k = idx >> 7, f = idx & 127;
        ldsWT[f * 136 + k] = f2bf(W[idx]);
    }
    __syncthreads();
    int nbase = blockIdx.x * 64;
    int row = nbase + w * 16 + r16;
    const float4* xr4 = (const float4*)(x + (size_t)row * FDIM);
    f32x4 acc[8] = {};
    for (int kb = 0; kb < 128; kb += 32) {
        float4 u0 = xr4[(kb >> 2) + klane * 2];
        float4 u1 = xr4[(kb >> 2) + klane * 2 + 1];
        union { short8 v; unsigned short u[8]; } a;
        a.u[0] = f2bf(u0.x); a.u[1] = f2bf(u0.y); a.u[2] = f2bf(u0.z); a.u[3] = f2bf(u0.w);
        a.u[4] = f2bf(u1.x); a.u[5] = f2bf(u1.y); a.u[6] = f2bf(u1.z); a.u[7] = f2bf(u1.w);
        #pragma unroll
        for (int fb = 0; fb < 8; ++fb) {
            short8 b = *(const short8*)&ldsWT[(fb * 16 + r16) * 136 + kb + klane * 8];
            acc[fb] = __builtin_amdgcn_mfma_f32_16x16x32_bf16(a.v, b, acc[fb], 0, 0, 0);
        }
    }
    // local node nl = w*16 + klane*4 + r; invp(nl) = 16*r + w*4 + klane
    #pragma unroll
    for (int fb = 0; fb < 8; ++fb)
        #pragma unroll
        for (int r = 0; r < 4; ++r)
            ldsT[(fb * 16 + r16) * 72 + 16 * r + w * 4 + klane] = f2bf(acc[fb][r]);
    __syncthreads();
    int f = t >> 1, part = t & 1;
    #pragma unroll
    for (int j = 0; j < 4; ++j)
        *(uint4*)&xwTp[(size_t)f * N_NODES + nbase + part * 32 + j * 8] =
            *(const uint4*)&ldsT[f * 72 + part * 32 + j * 8];
}

#define LOADP(Q0, Q1, BUF, p) do { \
    Q0 = brow0[(p)]; Q1 = brow1[(p)]; \
    const unsigned short* _src = bcol + (size_t)(p) * 64; \
    _Pragma("unroll") \
    for (int _fb = 0; _fb < 4; ++_fb) { \
        BUF[_fb * 2]     = *(const uint4*)(_src + _fb * fbstride); \
        BUF[_fb * 2 + 1] = *(const uint4*)(_src + _fb * fbstride + 32); \
    } } while (0)

#define COMPUTEP(Q0, Q1, BUF) do { \
    _Pragma("unroll") \
    for (int _s2 = 0; _s2 < 2; ++_s2) { \
        uint32_t _h0 = (uint32_t)(_s2 == 0 ? (Q0) : ((Q0) >> 32)); \
        uint32_t _h1 = (uint32_t)(_s2 == 0 ? (Q1) : ((Q1) >> 32)); \
        short8 _a0 = expand8(_h0, bitoff); \
        short8 _a1 = expand8(_h1, bitoff); \
        _Pragma("unroll") \
        for (int _f = 0; _f < 4; ++_f) { \
            short8 _b = as_s8(BUF[_f * 2 + _s2]); \
            acc[0][_f] = __builtin_amdgcn_mfma_f32_16x16x32_bf16(_a0, _b, acc[0][_f], 0, 0, 0); \
            acc[1][_f] = __builtin_amdgcn_mfma_f32_16x16x32_bf16(_a1, _b, acc[1][_f], 0, 0, 0); \
        } } } while (0)

// Barrier-free bit-GEMM, depth-3 register pipeline, compile-time NP pairs.
// Sequential pair order 0..NP-1 (bit-identical accumulation vs R7).
// Wave tile = 32 rows x 64 cols; block = 64 rows x 128 cols.
template<bool FINAL, int NP>
__global__ __launch_bounds__(256) void k_gemm_gen(
        const ull* __restrict__ bits, int krows,
        const unsigned short* __restrict__ BT, int K,
        float* __restrict__ Cout, const float* __restrict__ rowScale, int M) {
    static_assert(NP % 3 == 1 || NP % 3 == 2, "tail requires NP%3 in {1,2}");
    int t = threadIdx.x, lane = t & 63, w = t >> 6;
    int r16 = lane & 15, klane = lane >> 4;
    int bitoff = klane * 8;
    int wm = w >> 1, wf = w & 1;
    int mbase = blockIdx.x * 64 + wm * 32;
    int kq0 = blockIdx.z * NP;
    const ull* brow0 = bits + (size_t)(mbase + r16) * krows + kq0;
    const ull* brow1 = brow0 + (size_t)16 * krows;
    const unsigned short* bcol = BT + (size_t)(wf * 64 + r16) * K + (size_t)kq0 * 64 + klane * 8;
    const size_t fbstride = (size_t)16 * K;
    f32x4 acc[2][4] = {};
    ull qA0, qA1, qB0, qB1, qC0, qC1;
    uint4 bufA[8], bufB[8], bufC[8];
    LOADP(qA0, qA1, bufA, 0);
    LOADP(qB0, qB1, bufB, 1);
    LOADP(qC0, qC1, bufC, 2);
    for (int p = 0; p <= NP - 7; p += 3) {
        COMPUTEP(qA0, qA1, bufA); LOADP(qA0, qA1, bufA, p + 3);
        COMPUTEP(qB0, qB1, bufB); LOADP(qB0, qB1, bufB, p + 4);
        COMPUTEP(qC0, qC1, bufC); LOADP(qC0, qC1, bufC, p + 5);
    }
    if constexpr (NP % 3 == 1) {
        // buffers hold NP-4,NP-3,NP-2; remaining loads: NP-1
        COMPUTEP(qA0, qA1, bufA); LOADP(qA0, qA1, bufA, NP - 1);
        COMPUTEP(qB0, qB1, bufB);
        COMPUTEP(qC0, qC1, bufC);
        COMPUTEP(qA0, qA1, bufA);
    } else {
        // buffers hold NP-5,NP-4,NP-3; remaining loads: NP-2, NP-1
        COMPUTEP(qA0, qA1, bufA); LOADP(qA0, qA1, bufA, NP - 2);
        COMPUTEP(qB0, qB1, bufB); LOADP(qB0, qB1, bufB, NP - 1);
        COMPUTEP(qC0, qC1, bufC);
        COMPUTEP(qA0, qA1, bufA);
        COMPUTEP(qB0, qB1, bufB);
    }
    #pragma unroll
    for (int fr = 0; fr < 2; ++fr)
        #pragma unroll
        for (int fb = 0; fb < 4; ++fb)
            #pragma unroll
            for (int r = 0; r < 4; ++r) {
                int row = mbase + fr * 16 + klane * 4 + r;
                int col = wf * 64 + fb * 16 + r16;
                float v = acc[fr][fb][r];
                if (FINAL)
                    Cout[(size_t)row * FDIM + col] = rowScale[row] * v;
                else
                    Cout[(size_t)blockIdx.z * M * FDIM + (size_t)row * FDIM + col] = v;
            }
}

// K5b (R2-verbatim): reduce split-K partials, scale d_e_inv, permuted bf16
// emTp [128][E] (edge columns permuted within 64-chunks to match bit order).
__global__ __launch_bounds__(256) void k_reduce_scale_T(const float* __restrict__ partials,
        const float* __restrict__ deinv, unsigned short* __restrict__ emTp, int S) {
    __shared__ float lds[64 * 129];
    int t = threadIdx.x;
    int e0 = blockIdx.x * 64;
    for (int i = 0; i < 32; ++i) {
        int idx = i * 256 + t;
        int e_l = idx >> 7, f = idx & 127;
        float s = 0.f;
        for (int z = 0; z < S; ++z)
            s += partials[(size_t)z * N_EDGES * FDIM + (size_t)(e0 + e_l) * FDIM + f];
        lds[e_l * 129 + f] = s * deinv[e0 + e_l];
    }
    __syncthreads();
    for (int i = 0; i < 32; ++i) {
        int idx = i * 256 + t;
        int f = idx >> 6, j = idx & 63;
        int pj = 4 * (j & 15) + (j >> 4);
        emTp[(size_t)f * N_EDGES + e0 + j] = f2bf(lds[pj * 129 + f]);
    }
}

// K6b (R4-proven): out = dvinv * (partN[0] + partN[1]); grid 512.
__global__ __launch_bounds__(256) void k_finalN(const float* __restrict__ partN,
        const float* __restrict__ dvinv, float* __restrict__ out) {
    const float4* pa = (const float4*)partN;
    const float4* pb = (const float4*)(partN + (size_t)N_NODES * FDIM);
    float4* o4 = (float4*)out;
    int t = threadIdx.x;
    #pragma unroll
    for (int i = 0; i < 4; ++i) {
        int idx = blockIdx.x * 1024 + i * 256 + t;
        float4 a = pa[idx], b = pb[idx];
        float s = dvinv[idx >> 5];
        o4[idx] = make_float4((a.x + b.x) * s, (a.y + b.y) * s,
                              (a.z + b.z) * s, (a.w + b.w) * s);
    }
}

extern "C" void kernel_launch(void* const* d_in, const int* in_sizes, int n_in,
                              void* d_out, int out_size, void* d_ws, size_t ws_size,
                              hipStream_t stream) {
    const float* x = (const float*)d_in[0];
    const float* H = (const float*)d_in[1];
    const float* W = (const float*)d_in[2];
    float* out = (float*)d_out;
    char* ws = (char*)d_ws;

    ull* bitsNE = (ull*)(ws);                                   // 8 MB
    ull* bitsEN = (ull*)(ws + (8u << 20));                      // 8 MB
    unsigned short* xwTp = (unsigned short*)(ws + (16u << 20)); // 4 MB
    unsigned short* emTp = (unsigned short*)(ws + (20u << 20)); // 1 MB
    float* dvinv = (float*)(ws + (21u << 20));                  // 64 KB
    float* deinv = (float*)(ws + (21u << 20) + 65536);          // 16 KB
    float* partE = (float*)(ws + (22u << 20));                  // up to 8 * 2 MB
    float* partN = (float*)(ws + (38u << 20));                  // 2 * 8 MB

    bool big = ws_size >= ((38u << 20) + (size_t)2 * N_NODES * FDIM * 4);

    hipLaunchKernelGGL(k_bitpack, dim3(4096), dim3(256), 0, stream, H, bitsNE, dvinv);
    hipLaunchKernelGGL(k_transpose_bf, dim3(512), dim3(256), 0, stream, bitsNE, bitsEN);
    hipLaunchKernelGGL(k_edeg, dim3(1024), dim3(256), 0, stream, bitsEN, deinv);
    hipLaunchKernelGGL(k_xw, dim3(256), dim3(256), 0, stream, x, W, xwTp);
    if (big) {
        // 512-block GEMMs: 2 waves/SIMD latency overlap
        hipLaunchKernelGGL((k_gemm_gen<false, 32>), dim3(64, 1, 8), dim3(256), 0, stream,
                           bitsEN, N_NODES / 64, xwTp, N_NODES, partE, (const float*)nullptr,
                           N_EDGES);
        hipLaunchKernelGGL(k_reduce_scale_T, dim3(64), dim3(256), 0, stream, partE, deinv, emTp, 8);
        hipLaunchKernelGGL((k_gemm_gen<false, 32>), dim3(256, 1, 2), dim3(256), 0, stream,
                           bitsNE, N_EDGES / 64, emTp, N_EDGES, partN, (const float*)nullptr,
                           N_NODES);
        hipLaunchKernelGGL(k_finalN, dim3(512), dim3(256), 0, stream, partN, dvinv, out);
    } else {
        // R7-proven fallback
        hipLaunchKernelGGL((k_gemm_gen<false, 64>), dim3(64, 1, 4), dim3(256), 0, stream,
                           bitsEN, N_NODES / 64, xwTp, N_NODES, partE, (const float*)nullptr,
                           N_EDGES);
        hipLaunchKernelGGL(k_reduce_scale_T, dim3(64), dim3(256), 0, stream, partE, deinv, emTp, 4);
        hipLaunchKernelGGL((k_gemm_gen<true, 64>), dim3(256, 1, 1), dim3(256), 0, stream,
                           bitsNE, N_EDGES / 64, emTp, N_EDGES, out, dvinv,
                           N_NODES);
    }
}

// Round 9
// 288.464 us; speedup vs baseline: 1.0168x; 1.0168x over previous
//
#include <hip/hip_runtime.h>
#include <stdint.h>

#define N_NODES 16384
#define N_EDGES 4096
#define FDIM    128
#define EPSF    1e-6f

typedef __attribute__((ext_vector_type(8))) short short8;
typedef __attribute__((ext_vector_type(4))) float f32x4;
typedef unsigned long long ull;

__device__ __forceinline__ unsigned short f2bf(float f) {
    uint32_t u = __float_as_uint(f);
    return (unsigned short)((u + 0x7FFFu + ((u >> 16) & 1u)) >> 16);  // RNE
}
__device__ __forceinline__ short8 as_s8(uint4 v) {
    union { uint4 a; short8 b; } u; u.a = v; return u.b;
}

// Expand 8 H-bits (byte at bitoff of `half`) into 8 packed bf16 {0.0,1.0}.
__device__ __forceinline__ short8 expand8(uint32_t half, int bitoff) {
    uint32_t b8 = (half >> bitoff) & 0xFFu;
    uint32_t lo = ((b8 & 0xFu) * 0x00204081u) & 0x01010101u;
    uint32_t hi = ((b8 >> 4) * 0x00204081u) & 0x01010101u;
    union { short8 v; uint32_t u[4]; } a;
#if __has_builtin(__builtin_amdgcn_perm)
    a.u[0] = __builtin_amdgcn_perm(0u, lo, 0x04010400u) * 0x3F80u;
    a.u[1] = __builtin_amdgcn_perm(0u, lo, 0x04030402u) * 0x3F80u;
    a.u[2] = __builtin_amdgcn_perm(0u, hi, 0x04010400u) * 0x3F80u;
    a.u[3] = __builtin_amdgcn_perm(0u, hi, 0x04030402u) * 0x3F80u;
#else
    a.u[0] = ((lo & 1u)         | ((lo >> 8) & 1u) << 16) * 0x3F80u;
    a.u[1] = (((lo >> 16) & 1u) | ((lo >> 24) & 1u) << 16) * 0x3F80u;
    a.u[2] = ((hi & 1u)         | ((hi >> 8) & 1u) << 16) * 0x3F80u;
    a.u[3] = (((hi >> 16) & 1u) | ((hi >> 24) & 1u) << 16) * 0x3F80u;
#endif
    return a.v;
}

// 64x64 bit-matrix transpose across a wave: lane r holds row r; out(r,c)=in(c,r).
__device__ __forceinline__ ull bit_transpose64(ull q, int lane) {
    const ull M32 = 0xFFFFFFFF00000000ull, M16 = 0xFFFF0000FFFF0000ull,
              M8 = 0xFF00FF00FF00FF00ull, M4 = 0xF0F0F0F0F0F0F0F0ull,
              M2 = 0xCCCCCCCCCCCCCCCCull, M1 = 0xAAAAAAAAAAAAAAAAull;
#define TSTEP(d, Md) { ull tv = __shfl_xor(q, d, 64); \
    q = ((lane & d) == 0) ? ((q & ~Md) | ((tv << d) & Md)) \
                          : ((q & Md) | ((tv >> d) & ~Md)); }
    TSTEP(32, M32) TSTEP(16, M16) TSTEP(8, M8) TSTEP(4, M4) TSTEP(2, M2) TSTEP(1, M1)
#undef TSTEP
    return q;
}

// K1 (R2-verbatim): bitpack H rows -> bitsNE [N][E/64], permuted bit order
// p(j) = 4*(j&15) + (j>>4); exact d_v_inv via popcount. float4 loads (1KB/wave).
__global__ __launch_bounds__(256) void k_bitpack(const float* __restrict__ H,
        ull* __restrict__ bitsNE, float* __restrict__ dvinv) {
    int w = threadIdx.x >> 6, lane = threadIdx.x & 63;
    int n = blockIdx.x * 4 + w;
    const float4* hr = (const float4*)(H + (size_t)n * N_EDGES);
    ull* out = bitsNE + (size_t)n * (N_EDGES / 64);
    int cnt = 0;
    for (int c4 = 0; c4 < N_EDGES / 256; ++c4) {
        float4 v = hr[c4 * 64 + lane];
        ull b0 = __ballot(v.x > 0.5f);
        ull b1 = __ballot(v.y > 0.5f);
        ull b2 = __ballot(v.z > 0.5f);
        ull b3 = __ballot(v.w > 0.5f);
        cnt += __popcll(b0) + __popcll(b1) + __popcll(b2) + __popcll(b3);
        if (lane == 0) {
            #pragma unroll
            for (int q = 0; q < 4; ++q) {
                ull wq = ((b0 >> (16 * q)) & 0xFFFFull)
                       | (((b1 >> (16 * q)) & 0xFFFFull) << 16)
                       | (((b2 >> (16 * q)) & 0xFFFFull) << 32)
                       | (((b3 >> (16 * q)) & 0xFFFFull) << 48);
                out[c4 * 4 + q] = wq;
            }
        }
    }
    if (lane == 0) dvinv[n] = 1.0f / ((float)cnt + EPSF);
}

// K2 (R7-proven): butterfly bit transpose with permuted row indexing.
__global__ __launch_bounds__(256) void k_transpose_bf(const ull* __restrict__ bitsNE,
        ull* __restrict__ bitsEN) {
    int w = threadIdx.x >> 6, lane = threadIdx.x & 63;
    int wid = blockIdx.x * 4 + w;          // 0..2047
    int nt = wid >> 3, etg = wid & 7;
    int pl = 4 * (lane & 15) + (lane >> 4);
    const ull* src = bitsNE + (size_t)(nt * 64 + pl) * (N_EDGES / 64);
    #pragma unroll
    for (int i = 0; i < 8; ++i) {
        int et = etg * 8 + i;
        ull q = src[et];
        q = bit_transpose64(q, lane);
        bitsEN[(size_t)(et * 64 + pl) * (N_NODES / 64) + nt] = q;
    }
}

// K3 (R2-verbatim): edge degrees via popcount -> d_e_inv (exact).
__global__ __launch_bounds__(256) void k_edeg(const ull* __restrict__ bitsEN,
        float* __restrict__ deinv) {
    int w = threadIdx.x >> 6, lane = threadIdx.x & 63;
    int e = blockIdx.x * 4 + w;
    const ull* r = bitsEN + (size_t)e * (N_NODES / 64);
    int s = __popcll(r[lane]) + __popcll(r[lane + 64]) + __popcll(r[lane + 128]) + __popcll(r[lane + 192]);
    for (int o = 32; o; o >>= 1) s += __shfl_xor(s, o);
    if (lane == 0) deinv[e] = 1.0f / ((float)s + EPSF);
}

// K4 (R2-verbatim): xw = x @ W; transposed-permuted bf16 xwTp [128][N].
__global__ __launch_bounds__(256) void k_xw(const float* __restrict__ x, const float* __restrict__ W,
        unsigned short* __restrict__ xwTp) {
    __shared__ __attribute__((aligned(16))) unsigned short ldsWT[128 * 136];
    __shared__ __attribute__((aligned(16))) unsigned short ldsT[128 * 72];
    int t = threadIdx.x, lane = t & 63, w = t >> 6;
    int r16 = lane & 15, klane = lane >> 4;
    for (int i = 0; i < 64; ++i) {
        int idx = i * 256 + t;
        int k = idx >> 7, f = idx & 127;
        ldsWT[f * 136 + k] = f2bf(W[idx]);
    }
    __syncthreads();
    int nbase = blockIdx.x * 64;
    int row = nbase + w * 16 + r16;
    const float4* xr4 = (const float4*)(x + (size_t)row * FDIM);
    f32x4 acc[8] = {};
    for (int kb = 0; kb < 128; kb += 32) {
        float4 u0 = xr4[(kb >> 2) + klane * 2];
        float4 u1 = xr4[(kb >> 2) + klane * 2 + 1];
        union { short8 v; unsigned short u[8]; } a;
        a.u[0] = f2bf(u0.x); a.u[1] = f2bf(u0.y); a.u[2] = f2bf(u0.z); a.u[3] = f2bf(u0.w);
        a.u[4] = f2bf(u1.x); a.u[5] = f2bf(u1.y); a.u[6] = f2bf(u1.z); a.u[7] = f2bf(u1.w);
        #pragma unroll
        for (int fb = 0; fb < 8; ++fb) {
            short8 b = *(const short8*)&ldsWT[(fb * 16 + r16) * 136 + kb + klane * 8];
            acc[fb] = __builtin_amdgcn_mfma_f32_16x16x32_bf16(a.v, b, acc[fb], 0, 0, 0);
        }
    }
    // local node nl = w*16 + klane*4 + r; invp(nl) = 16*r + w*4 + klane
    #pragma unroll
    for (int fb = 0; fb < 8; ++fb)
        #pragma unroll
        for (int r = 0; r < 4; ++r)
            ldsT[(fb * 16 + r16) * 72 + 16 * r + w * 4 + klane] = f2bf(acc[fb][r]);
    __syncthreads();
    int f = t >> 1, part = t & 1;
    #pragma unroll
    for (int j = 0; j < 4; ++j)
        *(uint4*)&xwTp[(size_t)f * N_NODES + nbase + part * 32 + j * 8] =
            *(const uint4*)&ldsT[f * 72 + part * 32 + j * 8];
}

#define LOADP(Q0, Q1, BUF, p) do { \
    Q0 = brow0[(p)]; Q1 = brow1[(p)]; \
    const unsigned short* _src = bcol + (size_t)(p) * 64; \
    _Pragma("unroll") \
    for (int _fb = 0; _fb < 4; ++_fb) { \
        BUF[_fb * 2]     = *(const uint4*)(_src + _fb * fbstride); \
        BUF[_fb * 2 + 1] = *(const uint4*)(_src + _fb * fbstride + 32); \
    } } while (0)

#define COMPUTEP(Q0, Q1, BUF) do { \
    _Pragma("unroll") \
    for (int _s2 = 0; _s2 < 2; ++_s2) { \
        uint32_t _h0 = (uint32_t)(_s2 == 0 ? (Q0) : ((Q0) >> 32)); \
        uint32_t _h1 = (uint32_t)(_s2 == 0 ? (Q1) : ((Q1) >> 32)); \
        short8 _a0 = expand8(_h0, bitoff); \
        short8 _a1 = expand8(_h1, bitoff); \
        _Pragma("unroll") \
        for (int _f = 0; _f < 4; ++_f) { \
            short8 _b = as_s8(BUF[_f * 2 + _s2]); \
            acc[0][_f] = __builtin_amdgcn_mfma_f32_16x16x32_bf16(_a0, _b, acc[0][_f], 0, 0, 0); \
            acc[1][_f] = __builtin_amdgcn_mfma_f32_16x16x32_bf16(_a1, _b, acc[1][_f], 0, 0, 0); \
        } } } while (0)

// Node GEMM (R7-verbatim): depth-3 register pipeline, compile-time NP pairs.
// Wave tile = 32 rows x 64 cols; block = 64 rows x 128 cols (256 thr).
template<bool FINAL, int NP>
__global__ __launch_bounds__(256) void k_gemm_gen(
        const ull* __restrict__ bits, int krows,
        const unsigned short* __restrict__ BT, int K,
        float* __restrict__ Cout, const float* __restrict__ rowScale, int M) {
    static_assert(NP % 3 == 1 || NP % 3 == 2, "tail requires NP%3 in {1,2}");
    int t = threadIdx.x, lane = t & 63, w = t >> 6;
    int r16 = lane & 15, klane = lane >> 4;
    int bitoff = klane * 8;
    int wm = w >> 1, wf = w & 1;
    int mbase = blockIdx.x * 64 + wm * 32;
    int kq0 = blockIdx.z * NP;
    const ull* brow0 = bits + (size_t)(mbase + r16) * krows + kq0;
    const ull* brow1 = brow0 + (size_t)16 * krows;
    const unsigned short* bcol = BT + (size_t)(wf * 64 + r16) * K + (size_t)kq0 * 64 + klane * 8;
    const size_t fbstride = (size_t)16 * K;
    f32x4 acc[2][4] = {};
    ull qA0, qA1, qB0, qB1, qC0, qC1;
    uint4 bufA[8], bufB[8], bufC[8];
    LOADP(qA0, qA1, bufA, 0);
    LOADP(qB0, qB1, bufB, 1);
    LOADP(qC0, qC1, bufC, 2);
    for (int p = 0; p <= NP - 7; p += 3) {
        COMPUTEP(qA0, qA1, bufA); LOADP(qA0, qA1, bufA, p + 3);
        COMPUTEP(qB0, qB1, bufB); LOADP(qB0, qB1, bufB, p + 4);
        COMPUTEP(qC0, qC1, bufC); LOADP(qC0, qC1, bufC, p + 5);
    }
    if constexpr (NP % 3 == 1) {
        COMPUTEP(qA0, qA1, bufA); LOADP(qA0, qA1, bufA, NP - 1);
        COMPUTEP(qB0, qB1, bufB);
        COMPUTEP(qC0, qC1, bufC);
        COMPUTEP(qA0, qA1, bufA);
    } else {
        COMPUTEP(qA0, qA1, bufA); LOADP(qA0, qA1, bufA, NP - 2);
        COMPUTEP(qB0, qB1, bufB); LOADP(qB0, qB1, bufB, NP - 1);
        COMPUTEP(qC0, qC1, bufC);
        COMPUTEP(qA0, qA1, bufA);
        COMPUTEP(qB0, qB1, bufB);
    }
    #pragma unroll
    for (int fr = 0; fr < 2; ++fr)
        #pragma unroll
        for (int fb = 0; fb < 4; ++fb)
            #pragma unroll
            for (int r = 0; r < 4; ++r) {
                int row = mbase + fr * 16 + klane * 4 + r;
                int col = wf * 64 + fb * 16 + r16;
                float v = acc[fr][fb][r];
                if (FINAL)
                    Cout[(size_t)row * FDIM + col] = rowScale[row] * v;
                else
                    Cout[(size_t)blockIdx.z * M * FDIM + (size_t)row * FDIM + col] = v;
            }
}

// Edge GEMM (NEW): 512-thread block = 8 waves = 4 row-groups x 2 col-halves,
// block tile 128 rows x 128 cols -> 2 waves/SIMD TLP at 1 block/CU.
// Depth-2 pipeline (R2-proven ordering), NP=32. VGPR ~150 (cap 256 via bounds).
template<int NP>
__global__ __launch_bounds__(512, 2) void k_gemm_edge(
        const ull* __restrict__ bits, int krows,
        const unsigned short* __restrict__ BT, int K,
        float* __restrict__ Cout, int M) {
    static_assert(NP % 2 == 0, "depth-2 loop requires even NP");
    int t = threadIdx.x, lane = t & 63, w = t >> 6;     // w 0..7
    int r16 = lane & 15, klane = lane >> 4;
    int bitoff = klane * 8;
    int wm = w >> 1, wf = w & 1;                         // wm 0..3
    int mbase = blockIdx.x * 128 + wm * 32;
    int kq0 = blockIdx.z * NP;
    const ull* brow0 = bits + (size_t)(mbase + r16) * krows + kq0;
    const ull* brow1 = brow0 + (size_t)16 * krows;
    const unsigned short* bcol = BT + (size_t)(wf * 64 + r16) * K + (size_t)kq0 * 64 + klane * 8;
    const size_t fbstride = (size_t)16 * K;
    f32x4 acc[2][4] = {};
    ull qA0, qA1, qB0, qB1;
    uint4 bufA[8], bufB[8];
    LOADP(qA0, qA1, bufA, 0);
    for (int p = 0; p < NP; p += 2) {
        LOADP(qB0, qB1, bufB, p + 1);
        COMPUTEP(qA0, qA1, bufA);
        if (p + 2 < NP) LOADP(qA0, qA1, bufA, p + 2);
        COMPUTEP(qB0, qB1, bufB);
    }
    #pragma unroll
    for (int fr = 0; fr < 2; ++fr)
        #pragma unroll
        for (int fb = 0; fb < 4; ++fb)
            #pragma unroll
            for (int r = 0; r < 4; ++r) {
                int row = mbase + fr * 16 + klane * 4 + r;
                int col = wf * 64 + fb * 16 + r16;
                Cout[(size_t)blockIdx.z * M * FDIM + (size_t)row * FDIM + col] = acc[fr][fb][r];
            }
}

// K5b (R2-verbatim): reduce split-K partials, scale d_e_inv, permuted bf16
// emTp [128][E] (edge columns permuted within 64-chunks to match bit order).
__global__ __launch_bounds__(256) void k_reduce_scale_T(const float* __restrict__ partials,
        const float* __restrict__ deinv, unsigned short* __restrict__ emTp, int S) {
    __shared__ float lds[64 * 129];
    int t = threadIdx.x;
    int e0 = blockIdx.x * 64;
    for (int i = 0; i < 32; ++i) {
        int idx = i * 256 + t;
        int e_l = idx >> 7, f = idx & 127;
        float s = 0.f;
        for (int z = 0; z < S; ++z)
            s += partials[(size_t)z * N_EDGES * FDIM + (size_t)(e0 + e_l) * FDIM + f];
        lds[e_l * 129 + f] = s * deinv[e0 + e_l];
    }
    __syncthreads();
    for (int i = 0; i < 32; ++i) {
        int idx = i * 256 + t;
        int f = idx >> 6, j = idx & 63;
        int pj = 4 * (j & 15) + (j >> 4);
        emTp[(size_t)f * N_EDGES + e0 + j] = f2bf(lds[pj * 129 + f]);
    }
}

extern "C" void kernel_launch(void* const* d_in, const int* in_sizes, int n_in,
                              void* d_out, int out_size, void* d_ws, size_t ws_size,
                              hipStream_t stream) {
    const float* x = (const float*)d_in[0];
    const float* H = (const float*)d_in[1];
    const float* W = (const float*)d_in[2];
    float* out = (float*)d_out;
    char* ws = (char*)d_ws;

    ull* bitsNE = (ull*)(ws);                                   // 8 MB
    ull* bitsEN = (ull*)(ws + (8u << 20));                      // 8 MB
    unsigned short* xwTp = (unsigned short*)(ws + (16u << 20)); // 4 MB
    unsigned short* emTp = (unsigned short*)(ws + (20u << 20)); // 1 MB
    float* dvinv = (float*)(ws + (21u << 20));                  // 64 KB
    float* deinv = (float*)(ws + (21u << 20) + 65536);          // 16 KB
    float* partE = (float*)(ws + (22u << 20));                  // up to 8 * 2 MB

    bool big = ws_size >= ((22u << 20) + (size_t)8 * N_EDGES * FDIM * 4);

    hipLaunchKernelGGL(k_bitpack, dim3(4096), dim3(256), 0, stream, H, bitsNE, dvinv);
    hipLaunchKernelGGL(k_transpose_bf, dim3(512), dim3(256), 0, stream, bitsNE, bitsEN);
    hipLaunchKernelGGL(k_edeg, dim3(1024), dim3(256), 0, stream, bitsEN, deinv);
    hipLaunchKernelGGL(k_xw, dim3(256), dim3(256), 0, stream, x, W, xwTp);
    if (big) {
        // 512-thread 128-row-tile edge GEMM: 2 waves/SIMD, SE=8 (z-order sums
        // nodes sequentially -> bit-identical accumulation vs R7).
        hipLaunchKernelGGL((k_gemm_edge<32>), dim3(32, 1, 8), dim3(512), 0, stream,
                           bitsEN, N_NODES / 64, xwTp, N_NODES, partE, N_EDGES);
        hipLaunchKernelGGL(k_reduce_scale_T, dim3(64), dim3(256), 0, stream, partE, deinv, emTp, 8);
    } else {
        hipLaunchKernelGGL((k_gemm_gen<false, 64>), dim3(64, 1, 4), dim3(256), 0, stream,
                           bitsEN, N_NODES / 64, xwTp, N_NODES, partE, (const float*)nullptr,
                           N_EDGES);
        hipLaunchKernelGGL(k_reduce_scale_T, dim3(64), dim3(256), 0, stream, partE, deinv, emTp, 4);
    }
    hipLaunchKernelGGL((k_gemm_gen<true, 64>), dim3(256, 1, 1), dim3(256), 0, stream,
                       bitsNE, N_EDGES / 64, emTp, N_EDGES, out, dvinv,
                       N_NODES);
}

// Round 10
// 250.079 us; speedup vs baseline: 1.1729x; 1.1535x over previous
//
#include <hip/hip_runtime.h>
#include <stdint.h>

#define N_NODES 16384
#define N_EDGES 4096
#define FDIM    128
#define EPSF    1e-6f
#define NPAIRS  64   // K-words per GEMM pass (both GEMMs: 256/SE=64 and 64/1=64)

typedef __attribute__((ext_vector_type(8))) short short8;
typedef __attribute__((ext_vector_type(4))) float f32x4;
typedef unsigned long long ull;

__device__ __forceinline__ unsigned short f2bf(float f) {
    uint32_t u = __float_as_uint(f);
    return (unsigned short)((u + 0x7FFFu + ((u >> 16) & 1u)) >> 16);  // RNE
}
__device__ __forceinline__ short8 as_s8(uint4 v) {
    union { uint4 a; short8 b; } u; u.a = v; return u.b;
}

// Expand 8 H-bits (byte at bitoff of `half`) into 8 packed bf16 {0.0,1.0}.
__device__ __forceinline__ short8 expand8(uint32_t half, int bitoff) {
    uint32_t b8 = (half >> bitoff) & 0xFFu;
    uint32_t lo = ((b8 & 0xFu) * 0x00204081u) & 0x01010101u;
    uint32_t hi = ((b8 >> 4) * 0x00204081u) & 0x01010101u;
    union { short8 v; uint32_t u[4]; } a;
#if __has_builtin(__builtin_amdgcn_perm)
    a.u[0] = __builtin_amdgcn_perm(0u, lo, 0x04010400u) * 0x3F80u;
    a.u[1] = __builtin_amdgcn_perm(0u, lo, 0x04030402u) * 0x3F80u;
    a.u[2] = __builtin_amdgcn_perm(0u, hi, 0x04010400u) * 0x3F80u;
    a.u[3] = __builtin_amdgcn_perm(0u, hi, 0x04030402u) * 0x3F80u;
#else
    a.u[0] = ((lo & 1u)         | ((lo >> 8) & 1u) << 16) * 0x3F80u;
    a.u[1] = (((lo >> 16) & 1u) | ((lo >> 24) & 1u) << 16) * 0x3F80u;
    a.u[2] = ((hi & 1u)         | ((hi >> 8) & 1u) << 16) * 0x3F80u;
    a.u[3] = (((hi >> 16) & 1u) | ((hi >> 24) & 1u) << 16) * 0x3F80u;
#endif
    return a.v;
}

// 64x64 bit-matrix transpose across a wave: lane r holds row r; out(r,c)=in(c,r).
__device__ __forceinline__ ull bit_transpose64(ull q, int lane) {
    const ull M32 = 0xFFFFFFFF00000000ull, M16 = 0xFFFF0000FFFF0000ull,
              M8 = 0xFF00FF00FF00FF00ull, M4 = 0xF0F0F0F0F0F0F0F0ull,
              M2 = 0xCCCCCCCCCCCCCCCCull, M1 = 0xAAAAAAAAAAAAAAAAull;
#define TSTEP(d, Md) { ull tv = __shfl_xor(q, d, 64); \
    q = ((lane & d) == 0) ? ((q & ~Md) | ((tv << d) & Md)) \
                          : ((q & Md) | ((tv >> d) & ~Md)); }
    TSTEP(32, M32) TSTEP(16, M16) TSTEP(8, M8) TSTEP(4, M4) TSTEP(2, M2) TSTEP(1, M1)
#undef TSTEP
    return q;
}

// K1 (R2-verbatim): bitpack H rows -> bitsNE [N][E/64], permuted bit order
// p(j) = 4*(j&15) + (j>>4); exact d_v_inv via popcount. float4 loads (1KB/wave).
__global__ __launch_bounds__(256) void k_bitpack(const float* __restrict__ H,
        ull* __restrict__ bitsNE, float* __restrict__ dvinv) {
    int w = threadIdx.x >> 6, lane = threadIdx.x & 63;
    int n = blockIdx.x * 4 + w;
    const float4* hr = (const float4*)(H + (size_t)n * N_EDGES);
    ull* out = bitsNE + (size_t)n * (N_EDGES / 64);
    int cnt = 0;
    for (int c4 = 0; c4 < N_EDGES / 256; ++c4) {
        float4 v = hr[c4 * 64 + lane];
        ull b0 = __ballot(v.x > 0.5f);
        ull b1 = __ballot(v.y > 0.5f);
        ull b2 = __ballot(v.z > 0.5f);
        ull b3 = __ballot(v.w > 0.5f);
        cnt += __popcll(b0) + __popcll(b1) + __popcll(b2) + __popcll(b3);
        if (lane == 0) {
            #pragma unroll
            for (int q = 0; q < 4; ++q) {
                ull wq = ((b0 >> (16 * q)) & 0xFFFFull)
                       | (((b1 >> (16 * q)) & 0xFFFFull) << 16)
                       | (((b2 >> (16 * q)) & 0xFFFFull) << 32)
                       | (((b3 >> (16 * q)) & 0xFFFFull) << 48);
                out[c4 * 4 + q] = wq;
            }
        }
    }
    if (lane == 0) dvinv[n] = 1.0f / ((float)cnt + EPSF);
}

// K2 (R7-proven): butterfly bit transpose with permuted row indexing.
__global__ __launch_bounds__(256) void k_transpose_bf(const ull* __restrict__ bitsNE,
        ull* __restrict__ bitsEN) {
    int w = threadIdx.x >> 6, lane = threadIdx.x & 63;
    int wid = blockIdx.x * 4 + w;          // 0..2047
    int nt = wid >> 3, etg = wid & 7;
    int pl = 4 * (lane & 15) + (lane >> 4);
    const ull* src = bitsNE + (size_t)(nt * 64 + pl) * (N_EDGES / 64);
    #pragma unroll
    for (int i = 0; i < 8; ++i) {
        int et = etg * 8 + i;
        ull q = src[et];
        q = bit_transpose64(q, lane);
        bitsEN[(size_t)(et * 64 + pl) * (N_NODES / 64) + nt] = q;
    }
}

// K3 (R2-verbatim): edge degrees via popcount -> d_e_inv (exact).
__global__ __launch_bounds__(256) void k_edeg(const ull* __restrict__ bitsEN,
        float* __restrict__ deinv) {
    int w = threadIdx.x >> 6, lane = threadIdx.x & 63;
    int e = blockIdx.x * 4 + w;
    const ull* r = bitsEN + (size_t)e * (N_NODES / 64);
    int s = __popcll(r[lane]) + __popcll(r[lane + 64]) + __popcll(r[lane + 128]) + __popcll(r[lane + 192]);
    for (int o = 32; o; o >>= 1) s += __shfl_xor(s, o);
    if (lane == 0) deinv[e] = 1.0f / ((float)s + EPSF);
}

// K4 (R2-verbatim): xw = x @ W; transposed-permuted bf16 xwTp [128][N].
__global__ __launch_bounds__(256) void k_xw(const float* __restrict__ x, const float* __restrict__ W,
        unsigned short* __restrict__ xwTp) {
    __shared__ __attribute__((aligned(16))) unsigned short ldsWT[128 * 136];
    __shared__ __attribute__((aligned(16))) unsigned short ldsT[128 * 72];
    int t = threadIdx.x, lane = t & 63, w = t >> 6;
    int r16 = lane & 15, klane = lane >> 4;
    for (int i = 0; i < 64; ++i) {
        int idx = i * 256 + t;
        int k = idx >> 7, f = idx & 127;
        ldsWT[f * 136 + k] = f2bf(W[idx]);
    }
    __syncthreads();
    int nbase = blockIdx.x * 64;
    int row = nbase + w * 16 + r16;
    const float4* xr4 = (const float4*)(x + (size_t)row * FDIM);
    f32x4 acc[8] = {};
    for (int kb = 0; kb < 128; kb += 32) {
        float4 u0 = xr4[(kb >> 2) + klane * 2];
        float4 u1 = xr4[(kb >> 2) + klane * 2 + 1];
        union { short8 v; unsigned short u[8]; } a;
        a.u[0] = f2bf(u0.x); a.u[1] = f2bf(u0.y); a.u[2] = f2bf(u0.z); a.u[3] = f2bf(u0.w);
        a.u[4] = f2bf(u1.x); a.u[5] = f2bf(u1.y); a.u[6] = f2bf(u1.z); a.u[7] = f2bf(u1.w);
        #pragma unroll
        for (int fb = 0; fb < 8; ++fb) {
            short8 b = *(const short8*)&ldsWT[(fb * 16 + r16) * 136 + kb + klane * 8];
            acc[fb] = __builtin_amdgcn_mfma_f32_16x16x32_bf16(a.v, b, acc[fb], 0, 0, 0);
        }
    }
    // local node nl = w*16 + klane*4 + r; invp(nl) = 16*r + w*4 + klane
    #pragma unroll
    for (int fb = 0; fb < 8; ++fb)
        #pragma unroll
        for (int r = 0; r < 4; ++r)
            ldsT[(fb * 16 + r16) * 72 + 16 * r + w * 4 + klane] = f2bf(acc[fb][r]);
    __syncthreads();
    int f = t >> 1, part = t & 1;
    #pragma unroll
    for (int j = 0; j < 4; ++j)
        *(uint4*)&xwTp[(size_t)f * N_NODES + nbase + part * 32 + j * 8] =
            *(const uint4*)&ldsT[f * 72 + part * 32 + j * 8];
}

#define LOADP(Q0, Q1, BUF, p) do { \
    Q0 = brow0[(p)]; Q1 = brow1[(p)]; \
    const unsigned short* _src = bcol + (size_t)(p) * 64; \
    _Pragma("unroll") \
    for (int _fb = 0; _fb < 4; ++_fb) { \
        BUF[_fb * 2]     = *(const uint4*)(_src + _fb * fbstride); \
        BUF[_fb * 2 + 1] = *(const uint4*)(_src + _fb * fbstride + 32); \
    } } while (0)

#define COMPUTEP(Q0, Q1, BUF) do { \
    _Pragma("unroll") \
    for (int _s2 = 0; _s2 < 2; ++_s2) { \
        uint32_t _h0 = (uint32_t)(_s2 == 0 ? (Q0) : ((Q0) >> 32)); \
        uint32_t _h1 = (uint32_t)(_s2 == 0 ? (Q1) : ((Q1) >> 32)); \
        short8 _a0 = expand8(_h0, bitoff); \
        short8 _a1 = expand8(_h1, bitoff); \
        _Pragma("unroll") \
        for (int _f = 0; _f < 4; ++_f) { \
            short8 _b = as_s8(BUF[_f * 2 + _s2]); \
            acc[0][_f] = __builtin_amdgcn_mfma_f32_16x16x32_bf16(_a0, _b, acc[0][_f], 0, 0, 0); \
            acc[1][_f] = __builtin_amdgcn_mfma_f32_16x16x32_bf16(_a1, _b, acc[1][_f], 0, 0, 0); \
        } } } while (0)

// Barrier-free bit-GEMM, depth-3 register pipeline, NPAIRS=64 compile-time.
// Compute order over pairs is sequential 0..63 -> bit-identical to depth-2.
// Wave tile = 32 rows x 64 cols; block = 64 rows x 128 cols.
template<bool FINAL>
__global__ __launch_bounds__(256) void k_gemm_gen(
        const ull* __restrict__ bits, int krows,
        const unsigned short* __restrict__ BT, int K,
        float* __restrict__ Cout, const float* __restrict__ rowScale, int M) {
    int t = threadIdx.x, lane = t & 63, w = t >> 6;
    int r16 = lane & 15, klane = lane >> 4;
    int bitoff = klane * 8;
    int wm = w >> 1, wf = w & 1;
    int mbase = blockIdx.x * 64 + wm * 32;
    int kq0 = blockIdx.z * NPAIRS;
    const ull* brow0 = bits + (size_t)(mbase + r16) * krows + kq0;
    const ull* brow1 = brow0 + (size_t)16 * krows;
    const unsigned short* bcol = BT + (size_t)(wf * 64 + r16) * K + (size_t)kq0 * 64 + klane * 8;
    const size_t fbstride = (size_t)16 * K;
    f32x4 acc[2][4] = {};
    ull qA0, qA1, qB0, qB1, qC0, qC1;
    uint4 bufA[8], bufB[8], bufC[8];
    LOADP(qA0, qA1, bufA, 0);
    LOADP(qB0, qB1, bufB, 1);
    LOADP(qC0, qC1, bufC, 2);
    // main: 20 iters cover pairs 0..59, prefetch through 62 (NPAIRS=64: 64-7=57)
    for (int p = 0; p <= NPAIRS - 7; p += 3) {
        COMPUTEP(qA0, qA1, bufA); LOADP(qA0, qA1, bufA, p + 3);
        COMPUTEP(qB0, qB1, bufB); LOADP(qB0, qB1, bufB, p + 4);
        COMPUTEP(qC0, qC1, bufC); LOADP(qC0, qC1, bufC, p + 5);
    }
    // tail: pairs 60(A),61(B),62(C),63(A-reload)
    COMPUTEP(qA0, qA1, bufA); LOADP(qA0, qA1, bufA, NPAIRS - 1);
    COMPUTEP(qB0, qB1, bufB);
    COMPUTEP(qC0, qC1, bufC);
    COMPUTEP(qA0, qA1, bufA);
    #pragma unroll
    for (int fr = 0; fr < 2; ++fr)
        #pragma unroll
        for (int fb = 0; fb < 4; ++fb)
            #pragma unroll
            for (int r = 0; r < 4; ++r) {
                int row = mbase + fr * 16 + klane * 4 + r;
                int col = wf * 64 + fb * 16 + r16;
                float v = acc[fr][fb][r];
                if (FINAL)
                    Cout[(size_t)row * FDIM + col] = rowScale[row] * v;
                else
                    Cout[(size_t)blockIdx.z * M * FDIM + (size_t)row * FDIM + col] = v;
            }
}

// K5b (R2-verbatim): reduce split-K partials, scale d_e_inv, permuted bf16
// emTp [128][E] (edge columns permuted within 64-chunks to match bit order).
__global__ __launch_bounds__(256) void k_reduce_scale_T(const float* __restrict__ partials,
        const float* __restrict__ deinv, unsigned short* __restrict__ emTp, int S) {
    __shared__ float lds[64 * 129];
    int t = threadIdx.x;
    int e0 = blockIdx.x * 64;
    for (int i = 0; i < 32; ++i) {
        int idx = i * 256 + t;
        int e_l = idx >> 7, f = idx & 127;
        float s = 0.f;
        for (int z = 0; z < S; ++z)
            s += partials[(size_t)z * N_EDGES * FDIM + (size_t)(e0 + e_l) * FDIM + f];
        lds[e_l * 129 + f] = s * deinv[e0 + e_l];
    }
    __syncthreads();
    for (int i = 0; i < 32; ++i) {
        int idx = i * 256 + t;
        int f = idx >> 6, j = idx & 63;
        int pj = 4 * (j & 15) + (j >> 4);
        emTp[(size_t)f * N_EDGES + e0 + j] = f2bf(lds[pj * 129 + f]);
    }
}

extern "C" void kernel_launch(void* const* d_in, const int* in_sizes, int n_in,
                              void* d_out, int out_size, void* d_ws, size_t ws_size,
                              hipStream_t stream) {
    const float* x = (const float*)d_in[0];
    const float* H = (const float*)d_in[1];
    const float* W = (const float*)d_in[2];
    float* out = (float*)d_out;
    char* ws = (char*)d_ws;

    ull* bitsNE = (ull*)(ws);                                   // 8 MB
    ull* bitsEN = (ull*)(ws + (8u << 20));                      // 8 MB
    unsigned short* xwTp = (unsigned short*)(ws + (16u << 20)); // 4 MB
    unsigned short* emTp = (unsigned short*)(ws + (20u << 20)); // 1 MB
    float* dvinv = (float*)(ws + (21u << 20));                  // 64 KB
    float* deinv = (float*)(ws + (21u << 20) + 65536);          // 16 KB
    float* partE = (float*)(ws + (22u << 20));                  // 4 * 2 MB

    hipLaunchKernelGGL(k_bitpack, dim3(4096), dim3(256), 0, stream, H, bitsNE, dvinv);
    hipLaunchKernelGGL(k_transpose_bf, dim3(512), dim3(256), 0, stream, bitsNE, bitsEN);
    hipLaunchKernelGGL(k_edeg, dim3(1024), dim3(256), 0, stream, bitsEN, deinv);
    hipLaunchKernelGGL(k_xw, dim3(256), dim3(256), 0, stream, x, W, xwTp);
    hipLaunchKernelGGL((k_gemm_gen<false>), dim3(64, 1, 4), dim3(256), 0, stream,
                       bitsEN, N_NODES / 64, xwTp, N_NODES, partE, (const float*)nullptr,
                       N_EDGES);
    hipLaunchKernelGGL(k_reduce_scale_T, dim3(64), dim3(256), 0, stream, partE, deinv, emTp, 4);
    hipLaunchKernelGGL((k_gemm_gen<true>), dim3(256, 1, 1), dim3(256), 0, stream,
                       bitsNE, N_EDGES / 64, emTp, N_EDGES, out, dvinv,
                       N_NODES);
}